// Round 2
// baseline (64.073 us; speedup 1.0000x reference)
//
#include <hip/hip_runtime.h>
#include <hip/hip_bf16.h>
#include <math.h>

typedef __attribute__((ext_vector_type(8))) short short8;
typedef __attribute__((ext_vector_type(4))) float floatx4;

// LDS type-punning across barrier-free regions: defeat TBAA.
typedef unsigned int uint_a   __attribute__((may_alias));
typedef uint4        uint4_a  __attribute__((may_alias));
typedef short8       short8_a __attribute__((may_alias));

static __device__ __forceinline__ unsigned short bfbits(float f) {
    __hip_bfloat16 h = __float2bfloat16(f);
    unsigned short u;
    __builtin_memcpy(&u, &h, 2);
    return u;
}
static __device__ __forceinline__ unsigned pack2(float lo, float hi) {
    return (unsigned)bfbits(lo) | ((unsigned)bfbits(hi) << 16);
}

// ---- LDS strides ----
#define SP_STR  136   // u16; A-tiles (basis/silu), b128 frag reads (proven)
#define ST_STR  68    // f32; spline T tiles (gather banking proven at 68)
#define STB_STR 36    // f32; base T tile
#define SC_STR  132   // u8

// block (nb, s): rows [16nb,16nb+16), out cols [32s,32s+32).
// Operand-swapped spline MFMA: T^T = mfma(A=W^T frag from GLOBAL, B=P^T frag
// from sP). No spline-weight LDS tile at all: the W fragment (8 consecutive k
// for one fixed chunk-col) is 8 wave-coalesced dword loads from sw (L2-hot),
// packed straight to bf16 registers. sT content identical to verified kernel.
__global__ __launch_bounds__(256, 2) void kan_fused(
    const float* __restrict__ x,
    const float* __restrict__ bw,
    const float* __restrict__ sw,
    float* __restrict__ out)
{
    __shared__ short sP[5 * 16 * SP_STR];       // 21760 B
    __shared__ float sT[4 * 16 * ST_STR];       // 17408 B
    __shared__ float sTb[16 * STB_STR];         //  2304 B
    __shared__ unsigned char sC[16 * SC_STR];   //  2112 B  => 43584 B total

    const int tid = threadIdx.x;
    const int nb  = blockIdx.x >> 2;
    const int s   = blockIdx.x & 3;
    const int n0  = nb * 16;

    const int w = tid >> 6, l = tid & 63;
    const int m = l & 15, q = l >> 4;

    // ---- front-issue pre-barrier global loads ----
    const int r  = tid >> 4;
    const int i0 = (tid & 15) * 8;
    float v[8];
    *(float4*)(v)     = *(const float4*)(x + (n0 + r) * 128 + i0);
    *(float4*)(v + 4) = *(const float4*)(x + (n0 + r) * 128 + i0 + 4);

    const int cc = s + 4 * w;                       // this wave's spline chunk
    // per-lane W base: row (q*8), chunk col m  => addr sw[(q*8+..)*1024 + cc*64 + ..*16 + m]
    const float* gA = sw + cc * 64 + q * 8 * 1024 + m;

    // kh=0 fragment preload (latency hides under basis prologue)
    float f[2][4][8];
#pragma unroll
    for (int cg = 0; cg < 4; ++cg)
#pragma unroll
        for (int j2 = 0; j2 < 8; ++j2)
            f[0][cg][j2] = gA[j2 * 1024 + cg * 16];

    float4 bw8[8];
    if (w >= 2) {                                   // base B rows for cols 16(w-2)+m
        const float* bwp = bw + (32 * s + 16 * (w - 2) + m) * 128 + q * 8;
#pragma unroll
        for (int kk = 0; kk < 4; ++kk) {
            bw8[2 * kk]     = *(const float4*)(bwp + kk * 32);
            bw8[2 * kk + 1] = *(const float4*)(bwp + kk * 32 + 4);
        }
    }

    // ---- prologue: silu/u/c + basis for 16 rows x 128 feats (unchanged math) ----
    {
        float A5[5][8];
        unsigned char cc8[8];
#pragma unroll
        for (int i = 0; i < 8; ++i) {
            float xv = v[i];
            float si = xv / (1.0f + expf(-xv));
            float xn = fminf(fmaxf(xv, -1.0f), 1.0f);
            float t  = (xn + 2.2f) / 0.4f;         // (xn - G0)/H, bit-exact vs verified path
            float u  = t - floorf(t);
            int idx  = (int)floorf(t);
            idx = min(max(idx, 3), 7);
            cc8[i] = (unsigned char)(idx - 3);
            float u2 = u * u, u3 = u2 * u, om = 1.0f - u;
            A5[0][i] = om * om * om * (1.0f / 6.0f);
            A5[1][i] = 0.5f * u3 - u2 + (2.0f / 3.0f);
            A5[2][i] = -0.5f * u3 + 0.5f * u2 + 0.5f * u + (1.0f / 6.0f);
            A5[3][i] = u3 * (1.0f / 6.0f);
            A5[4][i] = si;
        }
#pragma unroll
        for (int g = 0; g < 5; ++g) {
            unsigned p0 = pack2(A5[g][0], A5[g][1]);
            unsigned p1 = pack2(A5[g][2], A5[g][3]);
            unsigned p2 = pack2(A5[g][4], A5[g][5]);
            unsigned p3 = pack2(A5[g][6], A5[g][7]);
            *(uint4_a*)(&sP[(g * 16 + r) * SP_STR + i0]) = make_uint4(p0, p1, p2, p3);
        }
        *(uint_a*)(&sC[r * SC_STR + i0])     = cc8[0] | (cc8[1]<<8) | (cc8[2]<<16) | (cc8[3]<<24);
        *(uint_a*)(&sC[r * SC_STR + i0 + 4]) = cc8[4] | (cc8[5]<<8) | (cc8[6]<<16) | (cc8[7]<<24);
    }

    __syncthreads();   // B1: sP/sC published

    // ---- spline GEMM, operand-swapped; 1-deep kh pipeline (static indices) ----
    floatx4 acc[4] = {{0.f,0.f,0.f,0.f},{0.f,0.f,0.f,0.f},
                      {0.f,0.f,0.f,0.f},{0.f,0.f,0.f,0.f}};
    const short* bp = &sP[(w * 16 + m) * SP_STR + q * 8];

#pragma unroll
    for (int kh = 0; kh < 4; ++kh) {
        if (kh < 3) {   // prefetch kh+1 fragments (independent; hides under MFMA)
#pragma unroll
            for (int cg = 0; cg < 4; ++cg)
#pragma unroll
                for (int j2 = 0; j2 < 8; ++j2)
                    f[(kh + 1) & 1][cg][j2] = gA[((kh + 1) * 32 + j2) * 1024 + cg * 16];
        }
        short8 bf = *(const short8_a*)(bp + kh * 32);   // P^T frag, reused over cg
#pragma unroll
        for (int cg = 0; cg < 4; ++cg) {
            uint4 pa = make_uint4(pack2(f[kh & 1][cg][0], f[kh & 1][cg][1]),
                                  pack2(f[kh & 1][cg][2], f[kh & 1][cg][3]),
                                  pack2(f[kh & 1][cg][4], f[kh & 1][cg][5]),
                                  pack2(f[kh & 1][cg][6], f[kh & 1][cg][7]));
            short8 af;
            __builtin_memcpy(&af, &pa, 16);
            acc[cg] = __builtin_amdgcn_mfma_f32_16x16x32_bf16(af, bf, acc[cg], 0, 0, 0);
        }
    }

    // ---- write spline T_w: lane(m,q) holds T[n=m][j=cg*16+q*4+rr] -> b128 ----
#pragma unroll
    for (int cg = 0; cg < 4; ++cg) {
        float4 st = make_float4(acc[cg][0], acc[cg][1], acc[cg][2], acc[cg][3]);
        *(float4*)(&sT[(w * 16 + m) * ST_STR + cg * 16 + q * 4]) = st;
    }

    // ---- base GEMM on waves 2,3: B packed straight from registers ----
    if (w >= 2) {
        const short* ap4 = &sP[(4 * 16 + m) * SP_STR + q * 8];
        floatx4 ab = {0.f, 0.f, 0.f, 0.f};
#pragma unroll
        for (int kk = 0; kk < 4; ++kk) {
            short8 af = *(const short8_a*)(ap4 + kk * 32);
            uint4 pb = make_uint4(pack2(bw8[2*kk].x,   bw8[2*kk].y),
                                  pack2(bw8[2*kk].z,   bw8[2*kk].w),
                                  pack2(bw8[2*kk+1].x, bw8[2*kk+1].y),
                                  pack2(bw8[2*kk+1].z, bw8[2*kk+1].w));
            short8 bf;
            __builtin_memcpy(&bf, &pb, 16);
            ab = __builtin_amdgcn_mfma_f32_16x16x32_bf16(af, bf, ab, 0, 0, 0);
        }
#pragma unroll
        for (int rr = 0; rr < 4; ++rr)
            sTb[(q * 4 + rr) * STB_STR + 16 * (w - 2) + m] = ab[rr];
    }

    __syncthreads();   // B2: all T ready

    // ---- gather + store (indexing identical to verified kernel) ----
    const int gn = tid >> 4, go2 = tid & 15;
    const int oh = 8 * s + (go2 >> 1);
    float racc0 = sTb[gn * STB_STR + 2 * go2];
    float racc1 = sTb[gn * STB_STR + 2 * go2 + 1];
#pragma unroll
    for (int j = 0; j < 4; ++j) {
        int c   = sC[gn * SC_STR + 32 * j + oh];
        int rel = 8 * (go2 >> 1) + c + 2 * (go2 & 1);
        racc0 += sT[(j * 16 + gn) * ST_STR + rel];
        racc1 += sT[(j * 16 + gn) * ST_STR + rel + 1];
    }
    *(float2*)(out + (n0 + gn) * 128 + 32 * s + 2 * go2) = make_float2(racc0, racc1);
}

extern "C" void kernel_launch(void* const* d_in, const int* in_sizes, int n_in,
                              void* d_out, int out_size, void* d_ws, size_t ws_size,
                              hipStream_t stream) {
    const float* x  = (const float*)d_in[0];
    const float* bw = (const float*)d_in[1];
    const float* sw = (const float*)d_in[2];
    float* out = (float*)d_out;
    kan_fused<<<dim3(512), dim3(256), 0, stream>>>(x, bw, sw, out);
}